// Round 20
// baseline (32.016 us; speedup 1.0000x reference)
//
#include <hip/hip_runtime.h>
#include <hip/hip_bf16.h>

#define CIN 32
#define HW 64
#define KK 64
#define NLEAF 8
#define PADDING 2
#define TT 8                    // tile rows = cols
#define WS 12                   // window rows/cols = TT + 4
#define WPOS (CIN * WS * WS)    // 4608 positions; f32x4 each -> 73728 B LDS

typedef float f32x4 __attribute__((ext_vector_type(4)));

__device__ __constant__ float d_C[16][4] = {
    {0, 0, 0, 0},  {0, 0, 0, 1},  {0, 1, 0, -1}, {0, 1, 0, 0},
    {0, 0, 1, -1}, {0, 0, 1, 0},  {0, 1, 1, -2}, {0, 1, 1, -1},
    {1, -1, -1, 1},{1, -1, -1, 2},{1, 0, -1, 0}, {1, 0, -1, 1},
    {1, -1, 0, 0}, {1, -1, 0, 1}, {1, 0, 0, -1}, {1, 0, 0, 0}
};

// Fully parallel prep: 4 blocks x 256 threads = 1024 threads.
// loffA[k*16+n] = ELEMENT offset of leaf (c,dh,dw) in the 32x12x12 window;
// tid<960: one coefA node each.
__global__ __launch_bounds__(256) void prep_kernel(
    const int* __restrict__ idx_h, const int* __restrict__ idx_w, const int* __restrict__ idx_c,
    const float* __restrict__ w0, const float* __restrict__ w1,
    const float* __restrict__ w2, const float* __restrict__ w3,
    float* __restrict__ coefA, int* __restrict__ loffA)
{
    int tid = blockIdx.x * 256 + threadIdx.x;   // 0..1023

    {
        int k = tid >> 4, n = tid & 15;
        int s = n >> 3, leaf = n & 7;
        int o = s * (KK * NLEAF) + k * NLEAF + leaf;
        loffA[tid] = idx_c[o] * (WS * WS) + idx_h[o] * WS + idx_w[o];
    }

    if (tid < KK * 15) {
        int k = tid / 15, node = tid % 15;
        const float* wp; int n;
        if (node < 8)       { wp = w0; n = node; }
        else if (node < 12) { wp = w1; n = node - 8; }
        else if (node < 14) { wp = w2; n = node - 12; }
        else                { wp = w3; n = 0; }
        const float4* lp = (const float4*)(wp + (size_t)(n * KK + k) * 16);
        float4 L0 = lp[0], L1 = lp[1], L2 = lp[2], L3 = lp[3];
        float l[16] = {L0.x, L0.y, L0.z, L0.w, L1.x, L1.y, L1.z, L1.w,
                       L2.x, L2.y, L2.z, L2.w, L3.x, L3.y, L3.z, L3.w};
        float m = l[0];
        #pragma unroll
        for (int g = 1; g < 16; ++g) m = fmaxf(m, l[g]);
        float p[16], s = 0.f;
        #pragma unroll
        for (int g = 0; g < 16; ++g) { p[g] = __expf(l[g] - m); s += p[g]; }
        float inv = 1.f / s;
        float c0 = 0, c1 = 0, c2 = 0, c3 = 0;
        #pragma unroll
        for (int g = 0; g < 16; ++g) {
            float w = p[g] * inv;
            c0 = fmaf(w, d_C[g][0], c0);
            c1 = fmaf(w, d_C[g][1], c1);
            c2 = fmaf(w, d_C[g][2], c2);
            c3 = fmaf(w, d_C[g][3], c3);
        }
        float* o = coefA + (k * 60 + node * 4);
        o[0] = c0; o[1] = c1; o[2] = c2; o[3] = c3;
    }
}

__device__ __forceinline__ f32x4 bc4(float s) { return (f32x4){s, s, s, s}; }
__device__ __forceinline__ f32x4 gate4(const float* c, f32x4 a, f32x4 b) {
    return __builtin_elementwise_fma(b,
               __builtin_elementwise_fma(a, bc4(c[3]), bc4(c[2])),
               __builtin_elementwise_fma(a, bc4(c[1]), bc4(c[0])));
}

// blockIdx = tile*4 + quad (256 blocks; quad q lands on XCDs {q, q+4}).
// ONE staged window serves ALL 64 k: 512 threads = 8 waves; wave w covers
// k in [8w, 8w+8). Tile 8x8 px, lane = pixel; window 32x12x12 f32x4 =
// 73.7 KB -> 2 blocks/CU (16 waves) preserved. f32x4 = 4 batch images.
__global__ __launch_bounds__(512, 4) void logic_conv_kernel(
    const float* __restrict__ x, const int* __restrict__ loffA,
    const float* __restrict__ coefA, float* __restrict__ out)
{
    extern __shared__ f32x4 xt[];   // 73728 B

    int tid  = threadIdx.x;
    int quad = blockIdx.x & 3;
    int t    = blockIdx.x >> 2;        // tile 0..63 (8x8 grid of 8x8 tiles)
    int r0   = (t >> 3) * TT;
    int c0   = (t & 7) * TT;

    const float* xb0 = x + (size_t)(4 * quad) * (CIN * HW * HW);
    const float* xb1 = xb0 + (CIN * HW * HW);
    const float* xb2 = xb1 + (CIN * HW * HW);
    const float* xb3 = xb2 + (CIN * HW * HW);

    // Stage packed padded 32x12x12 windows for 4 images (9 positions/thread).
    #pragma unroll
    for (int i = 0; i < 9; ++i) {
        int e  = tid + i * 512;
        int c  = e / (WS * WS);
        int r  = e - c * (WS * WS);
        int rr = r / WS;
        int cc = r - rr * WS;
        int ih = r0 + rr - PADDING, iw = c0 + cc - PADDING;
        f32x4 v = {0.f, 0.f, 0.f, 0.f};
        if ((unsigned)ih < HW && (unsigned)iw < HW) {
            int go = (c * HW + ih) * HW + iw;
            v.x = xb0[go];
            v.y = xb1[go];
            v.z = xb2[go];
            v.w = xb3[go];
        }
        xt[e] = v;
    }
    __syncthreads();

    int lane = tid & 63, wave = tid >> 6;
    int tr = lane >> 3, tc = lane & 7;
    int pxe   = tr * WS + tc;                  // element offset in window
    int pxout = (r0 + tr) * HW + (c0 + tc);    // output element offset
    float* outB0 = out + ((size_t)(4 * quad) << 18);
    float* outB1 = outB0 + (1 << 18);
    float* outB2 = outB1 + (1 << 18);
    float* outB3 = outB2 + (1 << 18);

    int kbase = __builtin_amdgcn_readfirstlane(wave << 3);

    #pragma unroll 2
    for (int j = 0; j < 8; ++j) {
        int k = kbase + j;
        const int*   L = loffA + (k << 4);
        const float* C = coefA + k * 60;

        f32x4 g[16];
        #pragma unroll
        for (int n = 0; n < 16; ++n)
            g[n] = xt[L[n] + pxe];

        f32x4 v[8];
        #pragma unroll
        for (int n = 0; n < 8; ++n)
            v[n] = gate4(C + 4 * n, g[n], g[8 + n]);
        f32x4 u[4];
        #pragma unroll
        for (int n = 0; n < 4; ++n)
            u[n] = gate4(C + 32 + 4 * n, v[2 * n], v[2 * n + 1]);
        f32x4 t0 = gate4(C + 48, u[0], u[1]);
        f32x4 t1 = gate4(C + 52, u[2], u[3]);
        f32x4 r  = gate4(C + 56, t0, t1);

        int ko = (k << 12) + pxout;
        __builtin_nontemporal_store(r.x, &outB0[ko]);
        __builtin_nontemporal_store(r.y, &outB1[ko]);
        __builtin_nontemporal_store(r.z, &outB2[ko]);
        __builtin_nontemporal_store(r.w, &outB3[ko]);
    }
}

extern "C" void kernel_launch(void* const* d_in, const int* in_sizes, int n_in,
                              void* d_out, int out_size, void* d_ws, size_t ws_size,
                              hipStream_t stream) {
    const float* x     = (const float*)d_in[0];
    const int*   idx_h = (const int*)d_in[1];
    const int*   idx_w = (const int*)d_in[2];
    const int*   idx_c = (const int*)d_in[3];
    const float* w0    = (const float*)d_in[4];
    const float* w1    = (const float*)d_in[5];
    const float* w2    = (const float*)d_in[6];
    const float* w3    = (const float*)d_in[7];
    float* out   = (float*)d_out;

    float* coefA = (float*)d_ws;                      // 15,360 B
    int*   loffA = (int*)((char*)d_ws + 16384);       // 4,096 B

    hipLaunchKernelGGL(prep_kernel, dim3(4), dim3(256), 0, stream,
                       idx_h, idx_w, idx_c, w0, w1, w2, w3, coefA, loffA);
    // 64 tiles * 4 quads = 256 blocks, 512 threads, 73.7 KB dynamic LDS
    hipLaunchKernelGGL(logic_conv_kernel, dim3(256), dim3(512),
                       WPOS * sizeof(f32x4), stream,
                       x, loffA, coefA, out);
}

// Round 21
// 20.900 us; speedup vs baseline: 1.5319x; 1.5319x over previous
//
#include <hip/hip_runtime.h>
#include <hip/hip_bf16.h>

#define CIN 32
#define HW 64
#define KK 64
#define NLEAF 8
#define PADDING 2
#define TH 4                    // tile rows
#define TCW 16                  // tile cols
#define WR 8                    // window rows = TH + 4
#define WC 20                   // window cols = TCW + 4
#define WPOS (CIN * WR * WC)    // 5120 positions; f32x4 each -> 81920 B LDS

typedef float f32x2 __attribute__((ext_vector_type(2)));
typedef float f32x4 __attribute__((ext_vector_type(4)));

__device__ __constant__ float d_C[16][4] = {
    {0, 0, 0, 0},  {0, 0, 0, 1},  {0, 1, 0, -1}, {0, 1, 0, 0},
    {0, 0, 1, -1}, {0, 0, 1, 0},  {0, 1, 1, -2}, {0, 1, 1, -1},
    {1, -1, -1, 1},{1, -1, -1, 2},{1, 0, -1, 0}, {1, 0, -1, 1},
    {1, -1, 0, 0}, {1, -1, 0, 1}, {1, 0, 0, -1}, {1, 0, 0, 0}
};

// Fully parallel prep: 4 blocks x 256 threads = 1024 threads.
// loffA[k*16+n] = BYTE offset of leaf (c,dh,dw) in the f32x4 window;
// tid<960: one coefA node each.
__global__ __launch_bounds__(256) void prep_kernel(
    const int* __restrict__ idx_h, const int* __restrict__ idx_w, const int* __restrict__ idx_c,
    const float* __restrict__ w0, const float* __restrict__ w1,
    const float* __restrict__ w2, const float* __restrict__ w3,
    float* __restrict__ coefA, int* __restrict__ loffA)
{
    int tid = blockIdx.x * 256 + threadIdx.x;   // 0..1023

    {
        int k = tid >> 4, n = tid & 15;
        int s = n >> 3, leaf = n & 7;
        int o = s * (KK * NLEAF) + k * NLEAF + leaf;
        loffA[tid] = (idx_c[o] * (WR * WC) + idx_h[o] * WC + idx_w[o]) * 16;
    }

    if (tid < KK * 15) {
        int k = tid / 15, node = tid % 15;
        const float* wp; int n;
        if (node < 8)       { wp = w0; n = node; }
        else if (node < 12) { wp = w1; n = node - 8; }
        else if (node < 14) { wp = w2; n = node - 12; }
        else                { wp = w3; n = 0; }
        const float4* lp = (const float4*)(wp + (size_t)(n * KK + k) * 16);
        float4 L0 = lp[0], L1 = lp[1], L2 = lp[2], L3 = lp[3];
        float l[16] = {L0.x, L0.y, L0.z, L0.w, L1.x, L1.y, L1.z, L1.w,
                       L2.x, L2.y, L2.z, L2.w, L3.x, L3.y, L3.z, L3.w};
        float m = l[0];
        #pragma unroll
        for (int g = 1; g < 16; ++g) m = fmaxf(m, l[g]);
        float p[16], s = 0.f;
        #pragma unroll
        for (int g = 0; g < 16; ++g) { p[g] = __expf(l[g] - m); s += p[g]; }
        float inv = 1.f / s;
        float c0 = 0, c1 = 0, c2 = 0, c3 = 0;
        #pragma unroll
        for (int g = 0; g < 16; ++g) {
            float w = p[g] * inv;
            c0 = fmaf(w, d_C[g][0], c0);
            c1 = fmaf(w, d_C[g][1], c1);
            c2 = fmaf(w, d_C[g][2], c2);
            c3 = fmaf(w, d_C[g][3], c3);
        }
        float* o = coefA + (k * 60 + node * 4);
        o[0] = c0; o[1] = c1; o[2] = c2; o[3] = c3;
    }
}

__device__ __forceinline__ f32x2 bc(float s) { return (f32x2){s, s}; }
__device__ __forceinline__ f32x2 gate2(const float* c, f32x2 a, f32x2 b) {
    return __builtin_elementwise_fma(b,
               __builtin_elementwise_fma(a, bc(c[3]), bc(c[2])),
               __builtin_elementwise_fma(a, bc(c[1]), bc(c[0])));
}

// blockIdx = tile*8 + grp; grp = kh*4 + quad -> XCD slot. 512 threads = 8
// waves; wave w covers k in [kh*32 + 4w, +4). lane = pixel of the 4x16 tile;
// f32x4 = 4 batch images -> every gather is one ds_read_b128.
// KEY CHANGE vs r15: all 64 gather addresses are precomputed into VGPRs
// BEFORE the k-loop (loffA s_loads hide under staging) -> the k-loop's
// ds_reads issue with no preceding uniform-load latency; in-order DS
// returns let the compiler pipeline with counted lgkmcnt.
__global__ __launch_bounds__(512, 4) void logic_conv_kernel(
    const float* __restrict__ x, const int* __restrict__ loffA,
    const float* __restrict__ coefA, float* __restrict__ out)
{
    extern __shared__ f32x4 xt[];   // WPOS = 81920 B

    int tid  = threadIdx.x;
    int grp  = blockIdx.x & 7;
    int quad = grp & 3;
    int kh   = grp >> 2;
    int t    = blockIdx.x >> 3;        // tile 0..63
    int r0   = (t >> 2) * TH;
    int c0   = (t & 3) * TCW;

    int lane = tid & 63, wave = tid >> 6;
    int kbase = __builtin_amdgcn_readfirstlane(kh * 32 + wave * 4);
    int tr = lane >> 4, tc = lane & 15;
    int pxb = (tr * WC + tc) * 16;     // per-lane byte offset in window

    // ---- hoisted gather addresses: 4 k x 16 leaves (compile-time indexed) ----
    int ga[4][16];
    #pragma unroll
    for (int j = 0; j < 4; ++j) {
        const int* L = loffA + ((kbase + j) << 4);
        #pragma unroll
        for (int n = 0; n < 16; ++n)
            ga[j][n] = L[n] + pxb;
    }

    const float* xb0 = x + (size_t)(4 * quad) * (CIN * HW * HW);
    const float* xb1 = xb0 + (CIN * HW * HW);
    const float* xb2 = xb1 + (CIN * HW * HW);
    const float* xb3 = xb2 + (CIN * HW * HW);

    // Stage packed padded 32x8x20 windows for 4 images (10 positions/thread).
    #pragma unroll
    for (int i = 0; i < 10; ++i) {
        int e  = tid + i * 512;
        int c  = e / (WR * WC);
        int r  = e - c * (WR * WC);
        int rr = r / WC;
        int cc = r - rr * WC;
        int ih = r0 + rr - PADDING, iw = c0 + cc - PADDING;
        f32x4 v = {0.f, 0.f, 0.f, 0.f};
        if ((unsigned)ih < HW && (unsigned)iw < HW) {
            int go = (c * HW + ih) * HW + iw;
            v.x = xb0[go];
            v.y = xb1[go];
            v.z = xb2[go];
            v.w = xb3[go];
        }
        xt[e] = v;
    }
    __syncthreads();

    int pxout = (r0 + tr) * HW + (c0 + tc);    // output element offset
    float* outB0 = out + ((size_t)(4 * quad) << 18);
    float* outB1 = outB0 + (1 << 18);
    float* outB2 = outB1 + (1 << 18);
    float* outB3 = outB2 + (1 << 18);
    const char* xtb = (const char*)xt;

    #pragma unroll
    for (int j = 0; j < 4; ++j) {
        const float* C = coefA + (kbase + j) * 60;

        f32x2 gA[16], gB[16];
        #pragma unroll
        for (int n = 0; n < 16; ++n) {
            f32x4 gv = *(const f32x4*)(xtb + ga[j][n]);
            gA[n] = (f32x2){gv.x, gv.y};
            gB[n] = (f32x2){gv.z, gv.w};
        }

        f32x2 vA[8], vB[8];
        #pragma unroll
        for (int n = 0; n < 8; ++n) {
            vA[n] = gate2(C + 4 * n, gA[n], gA[8 + n]);
            vB[n] = gate2(C + 4 * n, gB[n], gB[8 + n]);
        }
        f32x2 uA[4], uB[4];
        #pragma unroll
        for (int n = 0; n < 4; ++n) {
            uA[n] = gate2(C + 32 + 4 * n, vA[2 * n], vA[2 * n + 1]);
            uB[n] = gate2(C + 32 + 4 * n, vB[2 * n], vB[2 * n + 1]);
        }
        f32x2 sA0 = gate2(C + 48, uA[0], uA[1]);
        f32x2 sA1 = gate2(C + 52, uA[2], uA[3]);
        f32x2 sB0 = gate2(C + 48, uB[0], uB[1]);
        f32x2 sB1 = gate2(C + 52, uB[2], uB[3]);
        f32x2 qA  = gate2(C + 56, sA0, sA1);
        f32x2 qB  = gate2(C + 56, sB0, sB1);

        int ko = ((kbase + j) << 12) + pxout;
        __builtin_nontemporal_store(qA.x, &outB0[ko]);
        __builtin_nontemporal_store(qA.y, &outB1[ko]);
        __builtin_nontemporal_store(qB.x, &outB2[ko]);
        __builtin_nontemporal_store(qB.y, &outB3[ko]);
    }
}

extern "C" void kernel_launch(void* const* d_in, const int* in_sizes, int n_in,
                              void* d_out, int out_size, void* d_ws, size_t ws_size,
                              hipStream_t stream) {
    const float* x     = (const float*)d_in[0];
    const int*   idx_h = (const int*)d_in[1];
    const int*   idx_w = (const int*)d_in[2];
    const int*   idx_c = (const int*)d_in[3];
    const float* w0    = (const float*)d_in[4];
    const float* w1    = (const float*)d_in[5];
    const float* w2    = (const float*)d_in[6];
    const float* w3    = (const float*)d_in[7];
    float* out   = (float*)d_out;

    float* coefA = (float*)d_ws;                      // 15,360 B
    int*   loffA = (int*)((char*)d_ws + 16384);       // 4,096 B

    hipLaunchKernelGGL(prep_kernel, dim3(4), dim3(256), 0, stream,
                       idx_h, idx_w, idx_c, w0, w1, w2, w3, coefA, loffA);
    // 64 tiles * (4 quads x 2 kh) = 512 blocks, 512 threads, 80 KB dynamic LDS
    hipLaunchKernelGGL(logic_conv_kernel, dim3(512), dim3(512),
                       WPOS * sizeof(f32x4), stream,
                       x, loffA, coefA, out);
}